// Round 1
// baseline (286.041 us; speedup 1.0000x reference)
//
#include <hip/hip_runtime.h>
#include <math.h>

// LinearAttention: out[n,l,h,m] = (phi(Q[l])·KV[:,m]) / (phi(Q[l])·Ksum + eps)
//   KV[d][m] = sum_s phi(K[s,d]) V[s,m],  Ksum[d] = sum_s phi(K[s,d])
//   phi(x) = elu(x)+1 = x>0 ? x+1 : exp(x)

#define N_B 8
#define S_LEN 8192
#define H_N 8
#define D_DIM 64
#define NH (N_B * H_N)
#define EPS 1e-6f

__device__ __forceinline__ float felu1(float x) {
    return x > 0.0f ? x + 1.0f : __expf(x);
}

// ---------------- Phase 1a: partial KV + Ksum per (n,h,chunk) ----------------
// grid = NH * nchunk blocks, 256 threads. Each block reduces S/nchunk rows.
__global__ __launch_bounds__(256) void kv_partial_kernel(
        const float* __restrict__ Kin, const float* __restrict__ Vin,
        float* __restrict__ kvp,   // [NH*nchunk][D*D]
        float* __restrict__ ksp,   // [NH*nchunk][D]
        int nchunk) {
    constexpr int TS = 16; // rows staged per iteration
    __shared__ __align__(16) float Ks[TS][D_DIM];
    __shared__ __align__(16) float Vs[TS][D_DIM];

    const int b  = blockIdx.x;
    const int nh = b / nchunk;
    const int c  = b % nchunk;
    const int n_i = nh / H_N, h_i = nh % H_N;
    const int clen = S_LEN / nchunk;
    const int s0 = c * clen;
    const int t  = threadIdx.x;
    const int ty = t >> 4;       // d-quad index 0..15
    const int tx = t & 15;       // m-quad index 0..15

    const size_t rowstride = (size_t)H_N * D_DIM;
    const float* Kbase = Kin + (size_t)n_i * S_LEN * rowstride + (size_t)h_i * D_DIM;
    const float* Vbase = Vin + (size_t)n_i * S_LEN * rowstride + (size_t)h_i * D_DIM;

    float acc[4][4] = {};
    float ksum = 0.0f;

    const int lrow = t >> 4;          // loader row 0..15
    const int lq   = (t & 15) * 4;    // loader float4 offset within row

    for (int sb = 0; sb < clen; sb += TS) {
        // ---- stage TS rows of K (feature-mapped) and V into LDS ----
        {
            const size_t roff = (size_t)(s0 + sb + lrow) * rowstride + lq;
            const float4 k4 = *(const float4*)(Kbase + roff);
            const float4 v4 = *(const float4*)(Vbase + roff);
            float4 kf;
            kf.x = felu1(k4.x); kf.y = felu1(k4.y);
            kf.z = felu1(k4.z); kf.w = felu1(k4.w);
            *(float4*)&Ks[lrow][lq] = kf;
            *(float4*)&Vs[lrow][lq] = v4;
        }
        __syncthreads();

        // ---- 4x4 register-tile outer-product accumulation ----
        #pragma unroll
        for (int r = 0; r < TS; ++r) {
            const float4 k4 = *(const float4*)&Ks[r][ty * 4];
            const float4 v4 = *(const float4*)&Vs[r][tx * 4];
            const float ka[4] = {k4.x, k4.y, k4.z, k4.w};
            const float va[4] = {v4.x, v4.y, v4.z, v4.w};
            #pragma unroll
            for (int i = 0; i < 4; ++i)
                #pragma unroll
                for (int j = 0; j < 4; ++j)
                    acc[i][j] += ka[i] * va[j];
        }
        // ---- Ksum: wave 0 sums the staged K columns ----
        if (t < D_DIM) {
            #pragma unroll
            for (int r = 0; r < TS; ++r) ksum += Ks[r][t];
        }
        __syncthreads();
    }

    // ---- write partials ----
    float* kvout = kvp + (size_t)b * (D_DIM * D_DIM);
    #pragma unroll
    for (int i = 0; i < 4; ++i)
        #pragma unroll
        for (int j = 0; j < 4; ++j)
            kvout[(ty * 4 + i) * D_DIM + tx * 4 + j] = acc[i][j];
    if (t < D_DIM) ksp[(size_t)b * D_DIM + t] = ksum;
}

// ---------------- Phase 1b: reduce partials -> final KV, Ksum ----------------
__global__ __launch_bounds__(256) void kv_reduce_kernel(
        const float* __restrict__ kvp, const float* __restrict__ ksp,
        float* __restrict__ KV, float* __restrict__ Ksum, int nchunk) {
    const int nh = blockIdx.x;
    const int t  = threadIdx.x;
    for (int e = t; e < D_DIM * D_DIM; e += 256) {
        float s = 0.0f;
        for (int c = 0; c < nchunk; ++c)
            s += kvp[((size_t)nh * nchunk + c) * (D_DIM * D_DIM) + e];
        KV[(size_t)nh * (D_DIM * D_DIM) + e] = s;
    }
    if (t < D_DIM) {
        float s = 0.0f;
        for (int c = 0; c < nchunk; ++c)
            s += ksp[((size_t)nh * nchunk + c) * D_DIM + t];
        Ksum[(size_t)nh * D_DIM + t] = s;
    }
}

// ---------------- Phase 2: out = (Q·KV) / (Q·Ksum + eps) ----------------
// grid = NH * (S/RPB) blocks, 256 threads. 16 threads per row x 4 m each.
__global__ __launch_bounds__(256) void out_kernel(
        const float* __restrict__ Qin, const float* __restrict__ KV,
        const float* __restrict__ Ksum, float* __restrict__ Out) {
    constexpr int RPB = 64;   // rows per block
    constexpr int QTS = 16;   // rows per inner tile (= 256/16)
    constexpr int QPAD = 68;  // padded Q row stride (keeps 16B align, breaks bank wrap)
    __shared__ __align__(16) float KVs[D_DIM][D_DIM];  // 16 KB
    __shared__ __align__(16) float Kss[D_DIM];
    __shared__ __align__(16) float Qs[QTS][QPAD];

    const int b    = blockIdx.x;
    const int nblk = S_LEN / RPB;
    const int nh   = b / nblk;
    const int rb   = b % nblk;
    const int n_i = nh / H_N, h_i = nh % H_N;
    const int t  = threadIdx.x;
    const int row = t >> 4;   // row within tile
    const int tx  = t & 15;   // m-quad

    // stage KV + Ksum (synced by the barrier inside the row loop)
    for (int e = t; e < D_DIM * D_DIM; e += 256)
        KVs[e >> 6][e & 63] = KV[(size_t)nh * (D_DIM * D_DIM) + e];
    if (t < D_DIM) Kss[t] = Ksum[(size_t)nh * D_DIM + t];

    const size_t rowstride = (size_t)H_N * D_DIM;
    const float* Qbase = Qin + (size_t)n_i * S_LEN * rowstride + (size_t)h_i * D_DIM;
    float*       Obase = Out + (size_t)n_i * S_LEN * rowstride + (size_t)h_i * D_DIM;

    const int lrow = t >> 4;
    const int lq   = (t & 15) * 4;

    for (int rt = 0; rt < RPB; rt += QTS) {
        const int srow = rb * RPB + rt;
        __syncthreads();  // Qs from previous iter fully consumed; KVs staged (iter 0)
        {
            const float4 q4 = *(const float4*)(Qbase + (size_t)(srow + lrow) * rowstride + lq);
            Qs[lrow][lq + 0] = felu1(q4.x);
            Qs[lrow][lq + 1] = felu1(q4.y);
            Qs[lrow][lq + 2] = felu1(q4.z);
            Qs[lrow][lq + 3] = felu1(q4.w);
        }
        __syncthreads();

        float acc0 = 0.f, acc1 = 0.f, acc2 = 0.f, acc3 = 0.f, zacc = 0.f;
        #pragma unroll
        for (int d0 = 0; d0 < D_DIM; d0 += 4) {
            const float4 q4  = *(const float4*)&Qs[row][d0];
            const float4 ks4 = *(const float4*)&Kss[d0];   // uniform -> broadcast
            zacc += q4.x * ks4.x + q4.y * ks4.y + q4.z * ks4.z + q4.w * ks4.w;
            const float qa[4] = {q4.x, q4.y, q4.z, q4.w};
            #pragma unroll
            for (int j = 0; j < 4; ++j) {
                const float4 kv4 = *(const float4*)&KVs[d0 + j][tx * 4];
                acc0 += qa[j] * kv4.x;
                acc1 += qa[j] * kv4.y;
                acc2 += qa[j] * kv4.z;
                acc3 += qa[j] * kv4.w;
            }
        }
        const float z = 1.0f / (zacc + EPS);
        float4 o;
        o.x = acc0 * z; o.y = acc1 * z; o.z = acc2 * z; o.w = acc3 * z;
        *(float4*)(Obase + (size_t)(srow + row) * rowstride + tx * 4) = o;
    }
}

extern "C" void kernel_launch(void* const* d_in, const int* in_sizes, int n_in,
                              void* d_out, int out_size, void* d_ws, size_t ws_size,
                              hipStream_t stream) {
    const float* q = (const float*)d_in[0];
    const float* k = (const float*)d_in[1];
    const float* v = (const float*)d_in[2];
    float* out = (float*)d_out;

    // pick chunk count that fits workspace (deterministic: ws_size fixed per run)
    int nchunk = 16;
    while (nchunk > 1) {
        size_t need = ((size_t)NH * nchunk * (D_DIM * D_DIM + D_DIM)
                       + (size_t)NH * (D_DIM * D_DIM + D_DIM)) * sizeof(float);
        if (need <= ws_size) break;
        nchunk >>= 1;
    }

    float* kvp  = (float*)d_ws;
    float* ksp  = kvp + (size_t)NH * nchunk * D_DIM * D_DIM;
    float* KVf  = ksp + (size_t)NH * nchunk * D_DIM;
    float* Ksum = KVf + (size_t)NH * D_DIM * D_DIM;

    kv_partial_kernel<<<NH * nchunk, 256, 0, stream>>>(k, v, kvp, ksp, nchunk);
    kv_reduce_kernel<<<NH, 256, 0, stream>>>(kvp, ksp, KVf, Ksum, nchunk);
    out_kernel<<<NH * (S_LEN / 64), 256, 0, stream>>>(q, KVf, Ksum, out);
}